// Round 12
// baseline (1183.281 us; speedup 1.0000x reference)
//
#include <hip/hip_runtime.h>
#include <math.h>

#define NFEAT 128
#define NSPEC 10

// ---------------------------------------------------------------------------
// Fused histograms: node species counts + edge receiver counts
// ---------------------------------------------------------------------------
__global__ void k_histboth(const int* __restrict__ species, const int* __restrict__ edge_index,
                           int* __restrict__ counts, int* __restrict__ ehist, int N, int E) {
    int i = blockIdx.x * blockDim.x + threadIdx.x;
    if (i < N) atomicAdd(&counts[species[i]], 1);
    if (i < E) atomicAdd(&ehist[edge_index[E + i]], 1);
}

// ---------------------------------------------------------------------------
// Species tile table (one block; serial part = 10 iters)
// ---------------------------------------------------------------------------
__global__ void k_build(const int* __restrict__ counts, int* __restrict__ cursor,
                        int4* __restrict__ table, int* __restrict__ nTiles) {
    __shared__ int off[NSPEC + 1], ts[NSPEC + 1], cnt[NSPEC];
    const int t = threadIdx.x;
    if (t == 0) {
        int o = 0, tt = 0;
        for (int s = 0; s < NSPEC; s++) {
            cnt[s] = counts[s];
            off[s] = o; ts[s] = tt;
            o += cnt[s]; tt += (cnt[s] + 63) >> 6;
        }
        off[NSPEC] = o; ts[NSPEC] = tt;
        nTiles[0] = tt;
    }
    __syncthreads();
    if (t < NSPEC) cursor[t] = off[t];
    int nt = ts[NSPEC];
    for (int i = t; i < nt; i += blockDim.x) {
        int s = 0;
        while (ts[s + 1] <= i) s++;
        int b = i - ts[s];
        table[i] = make_int4(s, off[s] + b * 64, min(64, cnt[s] - b * 64), 0);
    }
}

__global__ void k_scatter(const int* __restrict__ species, int* __restrict__ cursor,
                          int* __restrict__ sorted, int N) {
    int i = blockIdx.x * blockDim.x + threadIdx.x;
    if (i < N) {
        int p = atomicAdd(&cursor[species[i]], 1);
        sorted[p] = i;
    }
}

// single block, 256 threads: exclusive scan of ehist[N] -> ecursor
__global__ void k_escan(const int* __restrict__ ehist, int* __restrict__ ecursor, int N) {
    __shared__ int ssum[256];
    const int t = threadIdx.x;
    const int chunk = (N + 255) / 256;
    const int lo = t * chunk;
    const int hi = min(lo + chunk, N);
    int local = 0;
    for (int i = lo; i < hi; i++) local += ehist[i];
    ssum[t] = local;
    __syncthreads();
    for (int off = 1; off < 256; off <<= 1) {
        int x = (t >= off) ? ssum[t - off] : 0;
        __syncthreads();
        ssum[t] += x;
        __syncthreads();
    }
    int run = ssum[t] - local;
    for (int i = lo; i < hi; i++) {
        ecursor[i] = run;
        run += ehist[i];
    }
}

// ---------------------------------------------------------------------------
// Edge gather into receiver-sorted order (payload moved once, streamed later)
// ---------------------------------------------------------------------------
__global__ void k_egather(const int* __restrict__ edge_index, const float* __restrict__ edge_attrs,
                          const float* __restrict__ edge_feats, int* __restrict__ ecursor,
                          int* __restrict__ sendG, int* __restrict__ recvG,
                          float* __restrict__ sh0G, float* __restrict__ efG, int E) {
    int i = blockIdx.x * blockDim.x + threadIdx.x;
    if (i < E) {
        int r = edge_index[E + i];
        int p = atomicAdd(&ecursor[r], 1);
        sendG[p] = edge_index[i];
        recvG[p] = r;
        sh0G[p]  = edge_attrs[(long)i * 16];
        float4 v0 = *(const float4*)(edge_feats + (long)i * 8);
        float4 v1 = *(const float4*)(edge_feats + (long)i * 8 + 4);
        *(float4*)(efG + (long)p * 8)     = v0;
        *(float4*)(efG + (long)p * 8 + 4) = v1;
    }
}

// ---------------------------------------------------------------------------
// fp32 GEMM (unchanged): C[64-row tile x BC cols] = alpha * A @ B
// ---------------------------------------------------------------------------
template <int BC>
__global__ __launch_bounds__(256) void k_gemm(
    const float* __restrict__ A, int aStride,
    const float* __restrict__ B, int bStride, int bSpecStride,
    float* __restrict__ C, int cStride, int cChunkY,
    int M, float alpha,
    const int* __restrict__ sorted,
    const int4* __restrict__ table,
    const int* __restrict__ nTiles)
{
    __shared__ float At[128][64];
    __shared__ float Bs[128][BC];
    const int t = threadIdx.x;
    const int gy = blockIdx.y;

    int start, cnt, spec = 0;
    if (table) {
        if (blockIdx.x >= nTiles[0]) return;
        int4 te = table[blockIdx.x];
        spec = te.x; start = te.y; cnt = te.z;
    } else {
        start = blockIdx.x * 64;
        cnt = M - start;
        if (cnt <= 0) return;
        if (cnt > 64) cnt = 64;
    }

    {
        const float* Bp = B + (long)spec * bSpecStride + (long)gy * BC;
        constexpr int F4R = BC / 4;
        #pragma unroll
        for (int i = 0; i < (128 * F4R) / 256; i++) {
            int idx = t + 256 * i;
            int k = idx / F4R;
            int c = (idx % F4R) * 4;
            *(float4*)&Bs[k][c] = *(const float4*)(Bp + (long)k * bStride + c);
        }
    }
    {
        int r = t & 63;
        int kc = (t >> 6) * 32;
        if (r < cnt) {
            int grow = table ? sorted[start + r] : (start + r);
            const float4* src = (const float4*)(A + (long)grow * aStride + kc);
            #pragma unroll
            for (int i = 0; i < 8; i++) {
                float4 v = src[i];
                At[kc + 4*i + 0][r] = v.x;
                At[kc + 4*i + 1][r] = v.y;
                At[kc + 4*i + 2][r] = v.z;
                At[kc + 4*i + 3][r] = v.w;
            }
        } else {
            #pragma unroll
            for (int i = 0; i < 32; i++) At[kc + i][r] = 0.0f;
        }
    }
    __syncthreads();

    constexpr int CG   = BC / 4;
    constexpr int ROWS = BC / 16;
    const int c0 = (t % CG) * 4;
    const int r0 = (t / CG) * ROWS;
    float acc[ROWS][4] = {};
    #pragma unroll 8
    for (int k = 0; k < 128; k++) {
        float4 b = *(const float4*)&Bs[k][c0];
        float av[ROWS];
        #pragma unroll
        for (int i = 0; i < ROWS / 4; i++) {
            float4 a = *(const float4*)&At[k][r0 + 4 * i];
            av[4*i + 0] = a.x; av[4*i + 1] = a.y; av[4*i + 2] = a.z; av[4*i + 3] = a.w;
        }
        #pragma unroll
        for (int i = 0; i < ROWS; i++) {
            acc[i][0] += av[i] * b.x;
            acc[i][1] += av[i] * b.y;
            acc[i][2] += av[i] * b.z;
            acc[i][3] += av[i] * b.w;
        }
    }
    #pragma unroll
    for (int i = 0; i < ROWS; i++) {
        int r = r0 + i;
        if (r < cnt) {
            int grow = table ? sorted[start + r] : (start + r);
            float4 v = make_float4(acc[i][0] * alpha, acc[i][1] * alpha,
                                   acc[i][2] * alpha, acc[i][3] * alpha);
            *(float4*)&C[(long)gy * cChunkY + (long)grow * cStride + c0] = v;
        }
    }
}

// ---------------------------------------------------------------------------
// Fused h + skip kernel (unchanged)
// ---------------------------------------------------------------------------
__global__ __launch_bounds__(256) void k_hs(
    const float* __restrict__ A,        // node_feats (N,128)
    const float* __restrict__ Wup,      // (128,128)
    const float* __restrict__ Wsn,      // (128,10,128)
    float* __restrict__ h, float* __restrict__ skip,
    const int* __restrict__ sorted, const int4* __restrict__ table,
    const int* __restrict__ nTiles, float aH, float aSkip)
{
    __shared__ float At[128][64];
    __shared__ float Bs[128][64];
    const int t = threadIdx.x;
    const int gy = blockIdx.y;
    if (blockIdx.x >= nTiles[0]) return;
    int4 te = table[blockIdx.x];
    const int spec = te.x, start = te.y, cnt = te.z;

    { // gathered A tile (transposed)
        int r = t & 63, kc = (t >> 6) * 32;
        if (r < cnt) {
            int grow = sorted[start + r];
            const float4* src = (const float4*)(A + (long)grow * NFEAT + kc);
            #pragma unroll
            for (int i = 0; i < 8; i++) {
                float4 v = src[i];
                At[kc + 4*i + 0][r] = v.x;
                At[kc + 4*i + 1][r] = v.y;
                At[kc + 4*i + 2][r] = v.z;
                At[kc + 4*i + 3][r] = v.w;
            }
        } else {
            #pragma unroll
            for (int i = 0; i < 32; i++) At[kc + i][r] = 0.0f;
        }
    }
    const int c0 = (t & 15) * 4;
    const int r0 = (t >> 4) * 4;
    #pragma unroll
    for (int pass = 0; pass < 2; pass++) {
        {
            const float* Bp = pass == 0 ? (Wup + gy * 64)
                                        : (Wsn + spec * NFEAT + gy * 64);
            const int bStride = pass == 0 ? NFEAT : NFEAT * NSPEC;
            #pragma unroll
            for (int i = 0; i < 8; i++) {
                int idx = t + 256 * i;
                int k = idx >> 4;
                int c = (idx & 15) * 4;
                *(float4*)&Bs[k][c] = *(const float4*)(Bp + (long)k * bStride + c);
            }
        }
        __syncthreads();
        float acc[4][4] = {};
        #pragma unroll 8
        for (int k = 0; k < 128; k++) {
            float4 b = *(const float4*)&Bs[k][c0];
            float4 a = *(const float4*)&At[k][r0];
            float av[4] = {a.x, a.y, a.z, a.w};
            #pragma unroll
            for (int i = 0; i < 4; i++) {
                acc[i][0] += av[i] * b.x;
                acc[i][1] += av[i] * b.y;
                acc[i][2] += av[i] * b.z;
                acc[i][3] += av[i] * b.w;
            }
        }
        float* dst   = pass == 0 ? h : skip;
        float  alpha = pass == 0 ? aH : aSkip;
        #pragma unroll
        for (int i = 0; i < 4; i++) {
            int r = r0 + i;
            if (r < cnt) {
                int grow = sorted[start + r];
                float4 v = make_float4(acc[i][0] * alpha, acc[i][1] * alpha,
                                       acc[i][2] * alpha, acc[i][3] * alpha);
                *(float4*)&dst[(long)grow * NFEAT + gy * 64 + c0] = v;
            }
        }
        __syncthreads();
    }
}

// ---------------------------------------------------------------------------
// Edge kernel v3: lane = edge, MLP state entirely in REGISTERS.
// One 64-thread block (1 wave) owns 64 receiver-sorted edges; no barriers.
// Weights read via lane-uniform indices (scalar-cache path, not LDS).
// All loops statically unrolled so ta[]/tb[]/acc[] stay in VGPRs.
// LDS only: 32-col transpose chunk act2w[64][36] (9.2 KB) + meta (768 B)
// for the run-combined coalesced atomic scatter (lanes 0-31).
// ---------------------------------------------------------------------------
__global__ __launch_bounds__(64, 3) void k_edge(
    const int*   __restrict__ sendG,    // (E) receiver-sorted
    const int*   __restrict__ recvG,
    const float* __restrict__ sh0G,
    const float* __restrict__ efG,      // (E,8) receiver-sorted
    const float* __restrict__ W1,       // (8,64)
    const float* __restrict__ W2,       // (64,64)
    const float* __restrict__ W3,       // (64,64)
    const float* __restrict__ W4,       // (64,512) cols 0..127 used
    const float* __restrict__ h,        // (N,128) scaled
    float*       __restrict__ msgs0,    // (N,128) pre-zeroed
    int E)
{
    __shared__ float act2w[64 * 36];    // [edge][36] 32-col chunk, padded
    __shared__ int   sendS[64];
    __shared__ int   recvS[64];
    __shared__ float sh0S[64];

    const int lane = threadIdx.x;
    const long base = (long)blockIdx.x * 64;
    const int nE = (E - (int)base < 64) ? (E - (int)base) : 64;

    // stage meta (per-block, read broadcast in scatter)
    {
        int p = (int)base + lane;
        bool ok = lane < nE;
        sendS[lane] = ok ? sendG[p] : 0;
        recvS[lane] = ok ? recvG[p] : -1;
        sh0S[lane]  = ok ? sh0G[p]  : 0.0f;
    }

    // load this lane's edge features (coalesced 32B/lane)
    float ef[8];
    if (lane < nE) {
        float4 v0 = *(const float4*)(efG + (base + lane) * 8);
        float4 v1 = *(const float4*)(efG + (base + lane) * 8 + 4);
        ef[0] = v0.x; ef[1] = v0.y; ef[2] = v0.z; ef[3] = v0.w;
        ef[4] = v1.x; ef[5] = v1.y; ef[6] = v1.z; ef[7] = v1.w;
    } else {
        #pragma unroll
        for (int k = 0; k < 8; k++) ef[k] = 0.0f;
    }

    const float s1 = 0.3535533905932738f;  // 1/sqrt(8)
    const float s2 = 0.125f;               // 1/sqrt(64)

    float ta[64], tb[64];

    // ---- t1: ta = silu(ef @ W1 * s1) ----
    #pragma unroll
    for (int jc = 0; jc < 4; jc++) {
        float acc[16];
        #pragma unroll
        for (int u = 0; u < 16; u++) acc[u] = 0.0f;
        #pragma unroll
        for (int k = 0; k < 8; k++) {
            #pragma unroll
            for (int u = 0; u < 16; u++)
                acc[u] += ef[k] * W1[k * 64 + jc * 16 + u];   // uniform -> scalar
        }
        #pragma unroll
        for (int u = 0; u < 16; u++) {
            float x = acc[u] * s1;
            ta[jc * 16 + u] = x / (1.0f + __expf(-x));
        }
    }

    // ---- t2: tb = silu(ta @ W2 * s2) ----
    #pragma unroll
    for (int jc = 0; jc < 4; jc++) {
        float acc[16];
        #pragma unroll
        for (int u = 0; u < 16; u++) acc[u] = 0.0f;
        #pragma unroll
        for (int k = 0; k < 64; k++) {
            #pragma unroll
            for (int u = 0; u < 16; u++)
                acc[u] += ta[k] * W2[k * 64 + jc * 16 + u];
        }
        #pragma unroll
        for (int u = 0; u < 16; u++) {
            float x = acc[u] * s2;
            tb[jc * 16 + u] = x / (1.0f + __expf(-x));
        }
    }

    // ---- t3: ta = silu(tb @ W3 * s2) ----
    #pragma unroll
    for (int jc = 0; jc < 4; jc++) {
        float acc[16];
        #pragma unroll
        for (int u = 0; u < 16; u++) acc[u] = 0.0f;
        #pragma unroll
        for (int k = 0; k < 64; k++) {
            #pragma unroll
            for (int u = 0; u < 16; u++)
                acc[u] += tb[k] * W3[k * 64 + jc * 16 + u];
        }
        #pragma unroll
        for (int u = 0; u < 16; u++) {
            float x = acc[u] * s2;
            ta[jc * 16 + u] = x / (1.0f + __expf(-x));
        }
    }

    // ---- w0 (4 chunks of 32 cols) + transpose + run-combined scatter ----
    for (int ch = 0; ch < 4; ch++) {        // runtime loop: ch only in uniform addrs
        float out[32];
        #pragma unroll
        for (int u = 0; u < 32; u++) out[u] = 0.0f;
        #pragma unroll
        for (int k = 0; k < 64; k++) {
            #pragma unroll
            for (int u = 0; u < 32; u++)
                out[u] += ta[k] * W4[k * 512 + ch * 32 + u];
        }
        // write this lane's 32-col slice (row = edge), padded stride 36
        #pragma unroll
        for (int u = 0; u < 32; u += 4)
            *(float4*)&act2w[lane * 36 + u] =
                make_float4(out[u], out[u + 1], out[u + 2], out[u + 3]);
        // scatter chunk: lanes 0-31 = cols, serial over sorted edges.
        // Same wave -> LDS writes above are visible, no barrier needed.
        if (lane < 32) {
            int cur = -1;
            float sum = 0.0f;
            for (int e = 0; e < nE; e++) {
                int rcv = recvS[e];                 // broadcast read
                if (rcv != cur) {
                    if (cur >= 0)
                        atomicAdd(&msgs0[(long)cur * NFEAT + ch * 32 + lane], sum);
                    cur = rcv; sum = 0.0f;
                }
                float f = sh0S[e] * s2;
                int snd = sendS[e];
                float hv = h[(long)snd * NFEAT + ch * 32 + lane];  // 128B coalesced
                sum += act2w[e * 36 + lane] * f * hv;
            }
            if (cur >= 0)
                atomicAdd(&msgs0[(long)cur * NFEAT + ch * 32 + lane], sum);
        }
    }
}

// ---------------------------------------------------------------------------
extern "C" void kernel_launch(void* const* d_in, const int* in_sizes, int n_in,
                              void* d_out, int out_size, void* d_ws, size_t ws_size,
                              hipStream_t stream) {
    const float* node_feats = (const float*)d_in[1];
    const float* edge_attrs = (const float*)d_in[2];
    const float* edge_feats = (const float*)d_in[3];
    const int*   edge_index = (const int*)  d_in[4];
    const int*   species    = (const int*)  d_in[5];
    const float* Wsn        = (const float*)d_in[6];   // (128,10,128)
    const float* Wup        = (const float*)d_in[7];   // (128,128)
    const float* W1         = (const float*)d_in[8];   // (8,64)
    const float* W2         = (const float*)d_in[9];   // (64,64)
    const float* W3         = (const float*)d_in[10];  // (64,64)
    const float* W4         = (const float*)d_in[11];  // (64,512)
    const float* Wlin       = (const float*)d_in[12];  // (4,128,128) -> l=0
    const float* Wsm        = (const float*)d_in[13];  // (4,128,10,128) -> l=0
    const float* Wout       = (const float*)d_in[14];  // (128,128)

    const int N = in_sizes[5];
    const int E = in_sizes[4] / 2;
    const int NF = NFEAT;

    float* out     = (float*)d_out;
    float* message = out;               // (N,128)
    float* skip    = out + (long)N * NF;

    // workspace carve
    char* wsb = (char*)d_ws;
    size_t off = 0;
    auto carve = [&](size_t bytes) { void* p = wsb + off; off = (off + bytes + 255) & ~(size_t)255; return p; };
    float* h      = (float*)carve((size_t)N * NF * 4);
    float* msgs0  = (float*)carve((size_t)N * NF * 4);
    float* Tst    = (float*)carve((size_t)NSPEC * NF * NF * 4);
    float* Comb   = (float*)carve((size_t)NSPEC * NF * NF * 4);
    int*   sorted = (int*)carve((size_t)N * 4);
    int*   counts = (int*)carve(64);
    int*   cursor = (int*)carve(64);
    int*   nTiles = (int*)carve(16);
    int4*  table  = (int4*)carve(256 * 16);
    int*   ehist  = (int*)carve((size_t)N * 4);
    int*   ecursor= (int*)carve((size_t)N * 4);
    int*   sendG  = (int*)carve((size_t)E * 4);
    int*   recvG  = (int*)carve((size_t)E * 4);
    float* sh0G   = (float*)carve((size_t)E * 4);
    float* efG    = (float*)carve((size_t)E * 8 * 4);

    const float aH    = 1.0f / sqrtf((float)NF);
    const float aSkip = 1.0f / sqrtf((float)(NF * NSPEC));
    const float cTot  = 0.25f / ((float)NF * sqrtf((float)(NF * NSPEC)));

    hipMemsetAsync(counts, 0, 64, stream);
    hipMemsetAsync(ehist, 0, (size_t)N * 4, stream);
    hipMemsetAsync(msgs0, 0, (size_t)N * NF * 4, stream);

    // histograms, species table, node sort, edge scan + payload gather
    k_histboth<<<(max(N, E) + 255) / 256, 256, 0, stream>>>(species, edge_index, counts, ehist, N, E);
    k_build  <<<1, 256, 0, stream>>>(counts, cursor, table, nTiles);
    k_scatter<<<(N + 255) / 256, 256, 0, stream>>>(species, cursor, sorted, N);
    k_escan  <<<1, 256, 0, stream>>>(ehist, ecursor, N);
    k_egather<<<(E + 255) / 256, 256, 0, stream>>>(edge_index, edge_attrs, edge_feats,
                                                   ecursor, sendG, recvG, sh0G, efG, E);

    const int mTiles   = (N + 63) / 64;
    const int maxTiles = mTiles + NSPEC;

    // fused h + skip (one gathered A-tile, two B passes)
    k_hs<<<dim3(maxTiles, 2), 256, 0, stream>>>(
        node_feats, Wup, Wsn, h, skip, sorted, table, nTiles, aH, aSkip);

    // Tst[s] = W_lin0 @ Wsm0[:,s,:]             (BC=128, gy=species)
    k_gemm<128><<<dim3(2, NSPEC), 256, 0, stream>>>(
        Wlin, NF, Wsm, NF * NSPEC, 0, Tst, NF, NF * NF, NF, 1.0f, nullptr, nullptr, nullptr);

    // Comb = Tst(1280x128) @ W_out * cTot       (BC=128)
    k_gemm<128><<<dim3((NSPEC * NF) / 64, 1), 256, 0, stream>>>(
        Tst, NF, Wout, NF, 0, Comb, NF, NF, NSPEC * NF, cTot, nullptr, nullptr, nullptr);

    // edge MLP v3: 1 wave / 64 edges, registers + scalar weights, no barriers
    int eBlocks = (E + 63) / 64;
    k_edge<<<eBlocks, 64, 0, stream>>>(
        sendG, recvG, sh0G, efG, W1, W2, W3, W4, h, msgs0, E);

    // message = gatherGEMM(msgs0, Comb[s])      (BC=64)
    k_gemm<64><<<dim3(maxTiles, 2), 256, 0, stream>>>(
        msgs0, NF, Comb, NF, NF * NF, message, NF, 64, N, 1.0f, sorted, table, nTiles);
}